// Round 22
// baseline (37.606 us; speedup 1.0000x reference)
//
#include <hip/hip_runtime.h>

// CharacterCNN — DEDUPE-BY-12-BIT-KEY, 3 small dispatches, each parallel.
// key = m3i:8 | st1:1 | st2:1 | st19:1 | st20:1. uout[4096][64] direct.
//  K0 lut_kernel (45 blocks): conv pattern tables -> global tab (f16).
//     Block-per-row; thread-per-channel with register-cached weights.
//  K1 ucompute (256 blocks, 16 keys each): phase-1 gather from global tab
//     -> highway/proj MFMA with per-wave f32->f16 LDS slice staging -> uout.
//  K2 keyscatter (n_tok/64 blocks): keys from ids in-block -> coalesced
//     gather of uout rows -> out.

typedef _Float16 f16;
typedef __attribute__((ext_vector_type(8))) _Float16 f16x8;
typedef __attribute__((ext_vector_type(4))) float f32x4;

#define LC1   0
#define LRAW2 96
#define LT2   672
#define LRAW3 1696
#define LT3LO 5152
#define LT3HI 7200
#define TABSZ 9248
#define NKEYS 4096
#define CROW  232
#define UOUT_OFF 20480        // bytes; tab occupies [0, 18496)

__device__ __forceinline__ f16x8 hmax8(f16x8 a, f16x8 b) {
  return __builtin_elementwise_max(a, b);
}

__device__ __forceinline__ f16x8 pin8(f16x8 v) {
  union { f16x8 v; unsigned w[4]; } x; x.v = v;
  asm volatile("" : "+v"(x.w[0]), "+v"(x.w[1]), "+v"(x.w[2]), "+v"(x.w[3]) :: "memory");
  return x.v;
}

// x value for char-state s (0=pad,1=char0,2=char1), dim i
__device__ __forceinline__ float xs(const float* __restrict__ E, int s, int i) {
  return (s == 0) ? 0.f : E[(s - 1) * 16 + i];
}

// ---------------- K0: parallel table build ----------------
// bid 0..26:  LRAW3 row p=bid                (threads 0..127 = channel)
// bid 27..42: LT3LO/LT3HI subset s=bid-27    (threads 0..127 = channel)
// bid 43:     LRAW2 (parts 0,1) + LT2 (parts 2,3)
// bid 44:     LC1
__global__ __launch_bounds__(256) void lut_kernel(
    const float* __restrict__ E,
    const float* __restrict__ W1, const float* __restrict__ b1,
    const float* __restrict__ W2, const float* __restrict__ b2,
    const float* __restrict__ W3, const float* __restrict__ b3,
    f16* __restrict__ tab)
{
  const int tid = threadIdx.x;
  const int bid = blockIdx.x;

  if (bid < 27) {                       // ---- LRAW3 ----
    if (tid >= 128) return;
    const int c = tid, p = bid;
    const int sa = p / 9, sb = (p / 3) % 3, sc = p % 3;
    const float* w = W3 + c * 48;
    float acc = b3[c];
#pragma unroll
    for (int i = 0; i < 16; i++)
      acc += w[i * 3 + 0] * xs(E, sa, i) + w[i * 3 + 1] * xs(E, sb, i)
           + w[i * 3 + 2] * xs(E, sc, i);
    tab[LRAW3 + p * 128 + c] = (f16)acc;
    return;
  }
  if (bid < 43) {                       // ---- LT3LO / LT3HI ----
    if (tid >= 128) return;
    const int c = tid, s = bid - 27;
    const float* w = W3 + c * 48;
    float lo = -65504.f, hi = -65504.f;
#pragma unroll
    for (int b = 0; b < 4; b++) {
      if (!((s >> b) & 1)) continue;
      int pl = 13 + 3 * (b >> 1) + (b & 1);   // a=1 interior
      int ph = 22 + 3 * (b >> 1) + (b & 1);   // a=2 interior
      int sal = pl / 9, sbl = (pl / 3) % 3, scl = pl % 3;
      int sah = ph / 9, sbh = (ph / 3) % 3, sch = ph % 3;
      float al = b3[c], ah = b3[c];
#pragma unroll
      for (int i = 0; i < 16; i++) {
        al += w[i * 3 + 0] * xs(E, sal, i) + w[i * 3 + 1] * xs(E, sbl, i)
            + w[i * 3 + 2] * xs(E, scl, i);
        ah += w[i * 3 + 0] * xs(E, sah, i) + w[i * 3 + 1] * xs(E, sbh, i)
            + w[i * 3 + 2] * xs(E, sch, i);
      }
      lo = fmaxf(lo, al);
      hi = fmaxf(hi, ah);
    }
    tab[LT3LO + s * 128 + c] = (f16)lo;
    tab[LT3HI + s * 128 + c] = (f16)hi;
    return;
  }
  if (bid == 43) {                      // ---- LRAW2 + LT2 ----
    const int c = tid & 63, part = tid >> 6;
    const float* w = W2 + c * 32;
    if (part < 2) {                     // LRAW2 rows p0..p0+4
      int p0 = part * 5;
      int pend = part ? 9 : 5;
      for (int p = p0; p < pend; p++) {
        int sa = p / 3, sb = p % 3;
        float acc = b2[c];
#pragma unroll
        for (int i = 0; i < 16; i++)
          acc += w[i * 2 + 0] * xs(E, sa, i) + w[i * 2 + 1] * xs(E, sb, i);
        tab[LRAW2 + p * 64 + c] = (f16)acc;
      }
    } else {                            // LT2: 8 subsets per thread
      float u[4];
#pragma unroll
      for (int b = 0; b < 4; b++) {
        int p = 4 + 3 * (b >> 1) + (b & 1);
        int sa = p / 3, sb = p % 3;
        float acc = b2[c];
#pragma unroll
        for (int i = 0; i < 16; i++)
          acc += w[i * 2 + 0] * xs(E, sa, i) + w[i * 2 + 1] * xs(E, sb, i);
        u[b] = acc;
      }
      int s0 = (part - 2) * 8;
#pragma unroll
      for (int j = 0; j < 8; j++) {
        int s = s0 + j;
        float m = -65504.f;
#pragma unroll
        for (int b = 0; b < 4; b++)
          if ((s >> b) & 1) m = fmaxf(m, u[b]);
        tab[LT2 + s * 64 + c] = (f16)m;
      }
    }
    return;
  }
  {                                     // ---- LC1 ----
    if (tid >= 32) return;
    const int c = tid;
    const float* w = W1 + c * 16;
    float u1 = b1[c], u2 = b1[c];
#pragma unroll
    for (int i = 0; i < 16; i++) {
      u1 += w[i] * E[i];
      u2 += w[i] * E[16 + i];
    }
    tab[LC1 + 0 * 32 + c] = (f16)fmaxf(u1, u2);
    tab[LC1 + 1 * 32 + c] = (f16)u1;
    tab[LC1 + 2 * 32 + c] = (f16)u2;
  }
}

// stage 16 contiguous rows x 224 cols of f32 W into this wave's [16][232] f16
// buffer. LO=0: value; LO=1: residual (w - f16(w)). 64-lane coalesced.
__device__ __forceinline__ void stage_slice(const float* __restrict__ src,
                                            f16* wst, int lane, int LO) {
  const f32x4* s4 = (const f32x4*)src;
#pragma unroll
  for (int i = 0; i < 14; i++) {
    int idx = i * 64 + lane;
    int flat = idx * 4;
    int r = flat / 224, c = flat - r * 224;
    f32x4 v = s4[idx];
    union { f16 h[4]; unsigned u2[2]; } o;
    if (LO) {
      o.h[0] = (f16)(v[0] - (float)(f16)v[0]); o.h[1] = (f16)(v[1] - (float)(f16)v[1]);
      o.h[2] = (f16)(v[2] - (float)(f16)v[2]); o.h[3] = (f16)(v[3] - (float)(f16)v[3]);
    } else {
      o.h[0] = (f16)v[0]; o.h[1] = (f16)v[1]; o.h[2] = (f16)v[2]; o.h[3] = (f16)v[3];
    }
    *(uint2*)&wst[r * CROW + c] = *(uint2*)o.u2;
  }
}

// ---------------- K1: ucompute (global tab gather, staged MFMA) ----------------
__global__ __launch_bounds__(256) void ucompute_kernel(
    const f16* __restrict__ tab,
    const float* __restrict__ HtW, const float* __restrict__ HgW,
    const float* __restrict__ PW,
    const float* __restrict__ Htb, const float* __restrict__ Hgb,
    const float* __restrict__ Pb, float* __restrict__ uout)
{
  __shared__ __attribute__((aligned(16))) f16 cnn[16 * CROW];
  __shared__ __attribute__((aligned(16))) f16 wstage[4 * 16 * CROW];

  const int tid = threadIdx.x;
  const int bid = blockIdx.x;
  const int wave = tid >> 6, lane = tid & 63;
  const int kbase = bid * 16;
  const int lrow = lane & 15;
  const int kg8 = (lane >> 4) * 8;
  const int rr0 = (lane >> 4) * 4;

  // ---- masks from key = kbase + (tid>>4) ----
  const int p1row = tid >> 4;
  const int p1g = tid & 15;
  unsigned mw, mb;
  {
    unsigned key = (unsigned)(kbase + p1row);
    unsigned m3i = key & 255u;
    int st1 = 1 + (int)((key >> 8) & 1),  st2 = 1 + (int)((key >> 9) & 1);
    int st19 = 1 + (int)((key >> 10) & 1), st20 = 1 + (int)((key >> 11) & 1);
    unsigned m2i = 0, mchar = 0;
#pragma unroll
    for (int p = 0; p < 8; p++)
      if ((m3i >> p) & 1) {
        m2i |= (1u << (p >> 1)) | (1u << (p & 3));
        mchar |= (1u << ((p >> 2) & 1)) | (1u << ((p >> 1) & 1)) | (1u << (p & 1));
      }
    unsigned sel = (mchar == 3u) ? 0u : ((mchar & 1u) ? 1u : 2u);
    mw = m3i | (m2i << 8) | (sel << 12);
    mb = (unsigned)st1 | ((unsigned)(st20 * 3) << 4)
       | ((unsigned)(st1 * 3 + st2) << 8) | ((unsigned)(st19 * 9 + st20 * 3) << 16);
  }

  // ---- phase 1: gather from GLOBAL tab; ReLU clamp ----
  const f16x8 KZ = {0, 0, 0, 0, 0, 0, 0, 0};
  {
    const int m3 = mw & 255;
    f16x8 v = hmax8(*(const f16x8*)(tab + LT3LO + (m3 & 15) * 128 + p1g * 8),
                    *(const f16x8*)(tab + LT3HI + ((m3 >> 4) & 15) * 128 + p1g * 8));
    v = hmax8(v, *(const f16x8*)(tab + LRAW3 + ((mb >> 8) & 15) * 128 + p1g * 8));
    v = hmax8(v, *(const f16x8*)(tab + LRAW3 + ((mb >> 16) & 31) * 128 + p1g * 8));
    *(f16x8*)&cnn[p1row * CROW + 96 + p1g * 8] = hmax8(v, KZ);
    if (p1g < 8) {
      f16x8 u = *(const f16x8*)(tab + LT2 + ((mw >> 8) & 15) * 64 + p1g * 8);
      u = hmax8(u, *(const f16x8*)(tab + LRAW2 + (mb & 15) * 64 + p1g * 8));
      u = hmax8(u, *(const f16x8*)(tab + LRAW2 + ((mb >> 4) & 15) * 64 + p1g * 8));
      *(f16x8*)&cnn[p1row * CROW + 32 + p1g * 8] = hmax8(u, KZ);
    }
    if (p1g < 4) {
      int sel = (mw >> 12) & 3;
      f16x8 w = *(const f16x8*)(tab + LC1 + sel * 32 + p1g * 8);
      *(f16x8*)&cnn[p1row * CROW + p1g * 8] = hmax8(w, KZ);
    }
  }
  __syncthreads();

  // ---- A-fragments ----
  f16x8 af[7];
#pragma unroll
  for (int kf = 0; kf < 7; kf++)
    af[kf] = *(const f16x8*)&cnn[lrow * CROW + kf * 32 + kg8];
#pragma unroll
  for (int kf = 0; kf < 7; kf++) af[kf] = pin8(af[kf]);
  __syncthreads();   // all waves captured af before in-place hw writes

  f16* wst = &wstage[wave * 16 * CROW];

  // ---- highway: wave w -> nf = w, w+4, w+8, w+12(w<2); staged slices ----
  const int nf_cnt = (wave < 2) ? 4 : 3;
  for (int i = 0; i < nf_cnt; i++) {
    const int nf = wave + i * 4;
    const int col = nf * 16 + lrow;
    const float bt = Htb[col], bg = Hgb[col];
    f32x4 aT = {bt, bt, bt, bt};
    f32x4 aG = {bg, bg, bg, bg};
    stage_slice(HtW + (size_t)nf * 16 * 224, wst, lane, 0);
#pragma unroll
    for (int kf = 0; kf < 7; kf++)
      aT = __builtin_amdgcn_mfma_f32_16x16x32_f16(
          af[kf], *(const f16x8*)&wst[lrow * CROW + kf * 32 + kg8], aT, 0, 0, 0);
    stage_slice(HgW + (size_t)nf * 16 * 224, wst, lane, 0);
#pragma unroll
    for (int kf = 0; kf < 7; kf++)
      aG = __builtin_amdgcn_mfma_f32_16x16x32_f16(
          af[kf], *(const f16x8*)&wst[lrow * CROW + kf * 32 + kg8], aG, 0, 0, 0);
#pragma unroll
    for (int r = 0; r < 4; r++) {
      int row = rr0 + r;
      float t  = fmaxf(aT[r], 0.f);
      float gg = __builtin_amdgcn_rcpf(1.f + __expf(-aG[r]));
      float cv = (float)cnn[row * CROW + col];
      cnn[row * CROW + col] = (f16)(cv + gg * (t - cv));   // own cols only
    }
  }
  __syncthreads();   // hw complete before proj reads all cols

  // ---- projection: wave w -> nf = w; P hi then lo staged ----
  f16x8 ah[7];
#pragma unroll
  for (int kf = 0; kf < 7; kf++)
    ah[kf] = *(const f16x8*)&cnn[lrow * CROW + kf * 32 + kg8];
  {
    const int col = wave * 16 + lrow;
    const float bp = Pb[col];
    f32x4 ac = {bp, bp, bp, bp};
    stage_slice(PW + (size_t)wave * 16 * 224, wst, lane, 0);
#pragma unroll
    for (int kf = 0; kf < 7; kf++)
      ac = __builtin_amdgcn_mfma_f32_16x16x32_f16(
          ah[kf], *(const f16x8*)&wst[lrow * CROW + kf * 32 + kg8], ac, 0, 0, 0);
    stage_slice(PW + (size_t)wave * 16 * 224, wst, lane, 1);
#pragma unroll
    for (int kf = 0; kf < 7; kf++)
      ac = __builtin_amdgcn_mfma_f32_16x16x32_f16(
          ah[kf], *(const f16x8*)&wst[lrow * CROW + kf * 32 + kg8], ac, 0, 0, 0);
#pragma unroll
    for (int r = 0; r < 4; r++)
      uout[(size_t)(kbase + rr0 + r) * 64 + col] = ac[r];
  }
}

// ---------------- K2: key + coalesced scatter ----------------
__global__ __launch_bounds__(256) void keyscatter_kernel(
    const int* __restrict__ ids, const float* __restrict__ uout,
    float* __restrict__ out, int n_tok)
{
  __shared__ unsigned keys[64];
  const int tid = threadIdx.x;
  const int tok0 = blockIdx.x * 64;

  if (tid < 64) {
    unsigned key = 0;
    int t = tok0 + tid;
    if (t < n_tok) {
      const int4* idp4 = (const int4*)(ids + (size_t)t * 20);
      int st[21];
#pragma unroll
      for (int q = 0; q < 5; q++) {
        int4 v = idp4[q];
        st[q * 4 + 1] = v.x; st[q * 4 + 2] = v.y;   // raw 0/1
        st[q * 4 + 3] = v.z; st[q * 4 + 4] = v.w;
      }
      unsigned m3i = 0;
#pragma unroll
      for (int l = 1; l <= 18; l++)
        m3i |= 1u << ((st[l] << 2) | (st[l + 1] << 1) | st[l + 2]);
      key = m3i | ((unsigned)st[1] << 8) | ((unsigned)st[2] << 9)
          | ((unsigned)st[19] << 10) | ((unsigned)st[20] << 11);
    }
    keys[tid] = key;
  }
  __syncthreads();

  const int tl = tid >> 2, q = tid & 3;
  const int t = tok0 + tl;
  if (t >= n_tok) return;
  const f32x4* src = (const f32x4*)(uout + (size_t)keys[tl] * 64 + q * 16);
  f32x4 v0 = src[0], v1 = src[1], v2 = src[2], v3 = src[3];
  f32x4* dst = (f32x4*)(out + (size_t)t * 64 + q * 16);
  dst[0] = v0; dst[1] = v1; dst[2] = v2; dst[3] = v3;
}

extern "C" void kernel_launch(void* const* d_in, const int* in_sizes, int n_in,
                              void* d_out, int out_size, void* d_ws, size_t ws_size,
                              hipStream_t stream) {
  const int*   ids = (const int*)d_in[0];
  const float* E   = (const float*)d_in[1];
  const float* W1  = (const float*)d_in[2];
  const float* b1  = (const float*)d_in[3];
  const float* W2  = (const float*)d_in[4];
  const float* b2  = (const float*)d_in[5];
  const float* W3  = (const float*)d_in[6];
  const float* b3  = (const float*)d_in[7];
  const float* HtW = (const float*)d_in[8];
  const float* Htb = (const float*)d_in[9];
  const float* HgW = (const float*)d_in[10];
  const float* Hgb = (const float*)d_in[11];
  const float* PW  = (const float*)d_in[12];
  const float* Pb  = (const float*)d_in[13];
  float* out = (float*)d_out;
  char* ws = (char*)d_ws;
  f16* tab = (f16*)ws;
  float* uout = (float*)(ws + UOUT_OFF);
  const int n_tok = in_sizes[0] / 20;

  lut_kernel<<<45, 256, 0, stream>>>(E, W1, b1, W2, b2, W3, b3, tab);
  ucompute_kernel<<<NKEYS / 16, 256, 0, stream>>>(
      tab, HtW, HgW, PW, Htb, Hgb, Pb, uout);
  keyscatter_kernel<<<(n_tok + 63) / 64, 256, 0, stream>>>(ids, uout, out, n_tok);
}

// Round 23
// 28.286 us; speedup vs baseline: 1.3295x; 1.3295x over previous
//
#include <hip/hip_runtime.h>

// CharacterCNN — DEDUPE-BY-12-BIT-KEY, 3 dispatches, all-verified pieces.
// key = m3i:8 | st1:1 | st2:1 | st19:1 | st20:1. uout[4096][64] direct.
//  K0 prep: [bid 0..44]   parallel conv tables -> global tab   (R22 lut)
//           [bid 45..492] f16 frag-linear weight repack -> wsb (R15 prep)
//  K1 ucompute (256 blocks, 16 keys): tab gather -> highway/proj MFMA from
//     frag-linear wsb -> uout.                                 (R15)
//  K2 keyscatter (n_tok/64 blocks): in-block keys -> coalesced gather/store.

typedef _Float16 f16;
typedef __attribute__((ext_vector_type(8))) _Float16 f16x8;
typedef __attribute__((ext_vector_type(4))) float f32x4;

#define LC1   0
#define LRAW2 96
#define LT2   672
#define LRAW3 1696
#define LT3LO 5152
#define LT3HI 7200
// ws layout (bytes): tab f16[9248] at 0; wsb at WOFFB (258,048 B, ends
// 276,992); uout f32[4096*64] at UOUT_OFF.
#define WOFFB    18944
#define PBASE    100352      // f16-unit offset of P chunks inside wsb
#define NWTH     114688
#define UOUT_OFF 278528
#define NKEYS    4096
#define CROW     232
#define LUT_BLOCKS 45
#define REPACK_BLOCKS 448

__device__ __forceinline__ f16x8 hmax8(f16x8 a, f16x8 b) {
  return __builtin_elementwise_max(a, b);
}

__device__ __forceinline__ f16x8 pin8(f16x8 v) {
  union { f16x8 v; unsigned w[4]; } x; x.v = v;
  asm volatile("" : "+v"(x.w[0]), "+v"(x.w[1]), "+v"(x.w[2]), "+v"(x.w[3]) :: "memory");
  return x.v;
}

__device__ __forceinline__ float xs(const float* __restrict__ E, int s, int i) {
  return (s == 0) ? 0.f : E[(s - 1) * 16 + i];
}

// ---------------- K0: parallel tables + weight repack ----------------
__global__ __launch_bounds__(256) void prep_kernel(
    const float* __restrict__ E,
    const float* __restrict__ W1, const float* __restrict__ b1,
    const float* __restrict__ W2, const float* __restrict__ b2,
    const float* __restrict__ W3, const float* __restrict__ b3,
    const float* __restrict__ HtW, const float* __restrict__ HgW,
    const float* __restrict__ PW,
    f16* __restrict__ tab, f16* __restrict__ wsb)
{
  const int tid = threadIdx.x;
  const int bid = blockIdx.x;

  if (bid >= LUT_BLOCKS) {              // ---- weight repack (R15) ----
    int idx = (bid - LUT_BLOCKS) * 256 + tid;
    if (idx < NWTH) {
      int e, isG = 0, isP = 0;
      if (idx < 50176)        { e = idx; }
      else if (idx < 100352)  { e = idx - 50176; isG = 1; }
      else                    { e = idx - 100352; isP = 1; }
      int col = e / 224, k = e - col * 224;
      int nf = col >> 4, kf = k >> 5, kr = k & 31;
      int lane = (col & 15) + ((kr >> 3) << 4), j = kr & 7;
      if (!isP) {
        int off = nf * 7168 + (isG * 7 + kf) * 512 + lane * 8 + j;
        wsb[off] = (f16)(isG ? HgW[e] : HtW[e]);
      } else {
        float w = PW[e];
        f16 hi = (f16)w;
        int off = PBASE + nf * 7168 + kf * 512 + lane * 8 + j;
        wsb[off] = hi;
        wsb[off + 3584] = (f16)(w - (float)hi);
      }
    }
    return;
  }

  // ---- table part (R22): block-per-row, thread-per-channel ----
  if (bid < 27) {                       // LRAW3
    if (tid >= 128) return;
    const int c = tid, p = bid;
    const int sa = p / 9, sb = (p / 3) % 3, sc = p % 3;
    const float* w = W3 + c * 48;
    float acc = b3[c];
#pragma unroll
    for (int i = 0; i < 16; i++)
      acc += w[i * 3 + 0] * xs(E, sa, i) + w[i * 3 + 1] * xs(E, sb, i)
           + w[i * 3 + 2] * xs(E, sc, i);
    tab[LRAW3 + p * 128 + c] = (f16)acc;
    return;
  }
  if (bid < 43) {                       // LT3LO / LT3HI
    if (tid >= 128) return;
    const int c = tid, s = bid - 27;
    const float* w = W3 + c * 48;
    float lo = -65504.f, hi = -65504.f;
#pragma unroll
    for (int b = 0; b < 4; b++) {
      if (!((s >> b) & 1)) continue;
      int pl = 13 + 3 * (b >> 1) + (b & 1);
      int ph = 22 + 3 * (b >> 1) + (b & 1);
      int sal = pl / 9, sbl = (pl / 3) % 3, scl = pl % 3;
      int sah = ph / 9, sbh = (ph / 3) % 3, sch = ph % 3;
      float al = b3[c], ah = b3[c];
#pragma unroll
      for (int i = 0; i < 16; i++) {
        al += w[i * 3 + 0] * xs(E, sal, i) + w[i * 3 + 1] * xs(E, sbl, i)
            + w[i * 3 + 2] * xs(E, scl, i);
        ah += w[i * 3 + 0] * xs(E, sah, i) + w[i * 3 + 1] * xs(E, sbh, i)
            + w[i * 3 + 2] * xs(E, sch, i);
      }
      lo = fmaxf(lo, al);
      hi = fmaxf(hi, ah);
    }
    tab[LT3LO + s * 128 + c] = (f16)lo;
    tab[LT3HI + s * 128 + c] = (f16)hi;
    return;
  }
  if (bid == 43) {                      // LRAW2 + LT2
    const int c = tid & 63, part = tid >> 6;
    const float* w = W2 + c * 32;
    if (part < 2) {
      int p0 = part * 5;
      int pend = part ? 9 : 5;
      for (int p = p0; p < pend; p++) {
        int sa = p / 3, sb = p % 3;
        float acc = b2[c];
#pragma unroll
        for (int i = 0; i < 16; i++)
          acc += w[i * 2 + 0] * xs(E, sa, i) + w[i * 2 + 1] * xs(E, sb, i);
        tab[LRAW2 + p * 64 + c] = (f16)acc;
      }
    } else {
      float u[4];
#pragma unroll
      for (int b = 0; b < 4; b++) {
        int p = 4 + 3 * (b >> 1) + (b & 1);
        int sa = p / 3, sb = p % 3;
        float acc = b2[c];
#pragma unroll
        for (int i = 0; i < 16; i++)
          acc += w[i * 2 + 0] * xs(E, sa, i) + w[i * 2 + 1] * xs(E, sb, i);
        u[b] = acc;
      }
      int s0 = (part - 2) * 8;
#pragma unroll
      for (int j = 0; j < 8; j++) {
        int s = s0 + j;
        float m = -65504.f;
#pragma unroll
        for (int b = 0; b < 4; b++)
          if ((s >> b) & 1) m = fmaxf(m, u[b]);
        tab[LT2 + s * 64 + c] = (f16)m;
      }
    }
    return;
  }
  {                                     // LC1
    if (tid >= 32) return;
    const int c = tid;
    const float* w = W1 + c * 16;
    float u1 = b1[c], u2 = b1[c];
#pragma unroll
    for (int i = 0; i < 16; i++) {
      u1 += w[i] * E[i];
      u2 += w[i] * E[16 + i];
    }
    tab[LC1 + 0 * 32 + c] = (f16)fmaxf(u1, u2);
    tab[LC1 + 1 * 32 + c] = (f16)u1;
    tab[LC1 + 2 * 32 + c] = (f16)u2;
  }
}

// ---------------- K1: ucompute (R15 verbatim) ----------------
__global__ __launch_bounds__(256) void ucompute_kernel(
    const f16* __restrict__ tab, const f16* __restrict__ wsb,
    const float* __restrict__ Htb, const float* __restrict__ Hgb,
    const float* __restrict__ Pb, float* __restrict__ uout)
{
  __shared__ __attribute__((aligned(16))) f16 cnn[16 * CROW];

  const int tid = threadIdx.x;
  const int wave = tid >> 6, lane = tid & 63;
  const int kbase = blockIdx.x * 16;
  const int lrow = lane & 15;
  const int kg8 = (lane >> 4) * 8;
  const int rr0 = (lane >> 4) * 4;

  const int p1row = tid >> 4;
  const int p1g = tid & 15;
  unsigned mw, mb;
  {
    unsigned key = (unsigned)(kbase + p1row);
    unsigned m3i = key & 255u;
    int st1 = 1 + (int)((key >> 8) & 1),  st2 = 1 + (int)((key >> 9) & 1);
    int st19 = 1 + (int)((key >> 10) & 1), st20 = 1 + (int)((key >> 11) & 1);
    unsigned m2i = 0, mchar = 0;
#pragma unroll
    for (int p = 0; p < 8; p++)
      if ((m3i >> p) & 1) {
        m2i |= (1u << (p >> 1)) | (1u << (p & 3));
        mchar |= (1u << ((p >> 2) & 1)) | (1u << ((p >> 1) & 1)) | (1u << (p & 1));
      }
    unsigned sel = (mchar == 3u) ? 0u : ((mchar & 1u) ? 1u : 2u);
    mw = m3i | (m2i << 8) | (sel << 12);
    mb = (unsigned)st1 | ((unsigned)(st20 * 3) << 4)
       | ((unsigned)(st1 * 3 + st2) << 8) | ((unsigned)(st19 * 9 + st20 * 3) << 16);
  }

  const f16x8 KZ = {0, 0, 0, 0, 0, 0, 0, 0};
  {
    const int m3 = mw & 255;
    f16x8 v = hmax8(*(const f16x8*)(tab + LT3LO + (m3 & 15) * 128 + p1g * 8),
                    *(const f16x8*)(tab + LT3HI + ((m3 >> 4) & 15) * 128 + p1g * 8));
    v = hmax8(v, *(const f16x8*)(tab + LRAW3 + ((mb >> 8) & 15) * 128 + p1g * 8));
    v = hmax8(v, *(const f16x8*)(tab + LRAW3 + ((mb >> 16) & 31) * 128 + p1g * 8));
    *(f16x8*)&cnn[p1row * CROW + 96 + p1g * 8] = hmax8(v, KZ);
    if (p1g < 8) {
      f16x8 u = *(const f16x8*)(tab + LT2 + ((mw >> 8) & 15) * 64 + p1g * 8);
      u = hmax8(u, *(const f16x8*)(tab + LRAW2 + (mb & 15) * 64 + p1g * 8));
      u = hmax8(u, *(const f16x8*)(tab + LRAW2 + ((mb >> 4) & 15) * 64 + p1g * 8));
      *(f16x8*)&cnn[p1row * CROW + 32 + p1g * 8] = hmax8(u, KZ);
    }
    if (p1g < 4) {
      int sel = (mw >> 12) & 3;
      f16x8 w = *(const f16x8*)(tab + LC1 + sel * 32 + p1g * 8);
      *(f16x8*)&cnn[p1row * CROW + p1g * 8] = hmax8(w, KZ);
    }
  }
  __syncthreads();

  f16x8 af[7];
#pragma unroll
  for (int kf = 0; kf < 7; kf++)
    af[kf] = *(const f16x8*)&cnn[lrow * CROW + kf * 32 + kg8];
#pragma unroll
  for (int kf = 0; kf < 7; kf++) af[kf] = pin8(af[kf]);
  __syncthreads();   // all waves captured af before in-place hw writes

  const f16* wbase = wsb + lane * 8;
  const int nf_cnt = (wave < 2) ? 4 : 3;
  for (int i = 0; i < nf_cnt; i++) {
    const int nf = wave + i * 4;
    const int col = nf * 16 + lrow;
    const f16* p_ = wbase + nf * 7168;
    const float bt = Htb[col], bg = Hgb[col];
    f32x4 aT = {bt, bt, bt, bt};
    f32x4 aG = {bg, bg, bg, bg};
#pragma unroll
    for (int kf = 0; kf < 7; kf++) {
      f16x8 wTv = *(const f16x8*)(p_ + kf * 512);
      f16x8 wGv = *(const f16x8*)(p_ + 3584 + kf * 512);
      aT = __builtin_amdgcn_mfma_f32_16x16x32_f16(af[kf], wTv, aT, 0, 0, 0);
      aG = __builtin_amdgcn_mfma_f32_16x16x32_f16(af[kf], wGv, aG, 0, 0, 0);
    }
#pragma unroll
    for (int r = 0; r < 4; r++) {
      int row = rr0 + r;
      float t  = fmaxf(aT[r], 0.f);
      float gg = __builtin_amdgcn_rcpf(1.f + __expf(-aG[r]));
      float cv = (float)cnn[row * CROW + col];
      cnn[row * CROW + col] = (f16)(cv + gg * (t - cv));
    }
  }
  __syncthreads();

  f16x8 ah[7];
#pragma unroll
  for (int kf = 0; kf < 7; kf++)
    ah[kf] = *(const f16x8*)&cnn[lrow * CROW + kf * 32 + kg8];
  {
    const int col = wave * 16 + lrow;
    const float bp = Pb[col];
    f32x4 ac = {bp, bp, bp, bp};
    const f16* ph = wbase + PBASE + wave * 7168;
#pragma unroll
    for (int kf = 0; kf < 7; kf++) {
      f16x8 wh = *(const f16x8*)(ph + kf * 512);
      f16x8 wl = *(const f16x8*)(ph + 3584 + kf * 512);
      ac = __builtin_amdgcn_mfma_f32_16x16x32_f16(ah[kf], wh, ac, 0, 0, 0);
      ac = __builtin_amdgcn_mfma_f32_16x16x32_f16(ah[kf], wl, ac, 0, 0, 0);
    }
#pragma unroll
    for (int r = 0; r < 4; r++)
      uout[(size_t)(kbase + rr0 + r) * 64 + col] = ac[r];
  }
}

// ---------------- K2: key + coalesced scatter ----------------
__global__ __launch_bounds__(256) void keyscatter_kernel(
    const int* __restrict__ ids, const float* __restrict__ uout,
    float* __restrict__ out, int n_tok)
{
  __shared__ unsigned keys[64];
  const int tid = threadIdx.x;
  const int tok0 = blockIdx.x * 64;

  if (tid < 64) {
    unsigned key = 0;
    int t = tok0 + tid;
    if (t < n_tok) {
      const int4* idp4 = (const int4*)(ids + (size_t)t * 20);
      int st[21];
#pragma unroll
      for (int q = 0; q < 5; q++) {
        int4 v = idp4[q];
        st[q * 4 + 1] = v.x; st[q * 4 + 2] = v.y;   // raw 0/1
        st[q * 4 + 3] = v.z; st[q * 4 + 4] = v.w;
      }
      unsigned m3i = 0;
#pragma unroll
      for (int l = 1; l <= 18; l++)
        m3i |= 1u << ((st[l] << 2) | (st[l + 1] << 1) | st[l + 2]);
      key = m3i | ((unsigned)st[1] << 8) | ((unsigned)st[2] << 9)
          | ((unsigned)st[19] << 10) | ((unsigned)st[20] << 11);
    }
    keys[tid] = key;
  }
  __syncthreads();

  const int tl = tid >> 2, q = tid & 3;
  const int t = tok0 + tl;
  if (t >= n_tok) return;
  const f32x4* src = (const f32x4*)(uout + (size_t)keys[tl] * 64 + q * 16);
  f32x4 v0 = src[0], v1 = src[1], v2 = src[2], v3 = src[3];
  f32x4* dst = (f32x4*)(out + (size_t)t * 64 + q * 16);
  dst[0] = v0; dst[1] = v1; dst[2] = v2; dst[3] = v3;
}

extern "C" void kernel_launch(void* const* d_in, const int* in_sizes, int n_in,
                              void* d_out, int out_size, void* d_ws, size_t ws_size,
                              hipStream_t stream) {
  const int*   ids = (const int*)d_in[0];
  const float* E   = (const float*)d_in[1];
  const float* W1  = (const float*)d_in[2];
  const float* b1  = (const float*)d_in[3];
  const float* W2  = (const float*)d_in[4];
  const float* b2  = (const float*)d_in[5];
  const float* W3  = (const float*)d_in[6];
  const float* b3  = (const float*)d_in[7];
  const float* HtW = (const float*)d_in[8];
  const float* Htb = (const float*)d_in[9];
  const float* HgW = (const float*)d_in[10];
  const float* Hgb = (const float*)d_in[11];
  const float* PW  = (const float*)d_in[12];
  const float* Pb  = (const float*)d_in[13];
  float* out = (float*)d_out;
  char* ws = (char*)d_ws;
  f16* tab = (f16*)ws;
  f16* wsb = (f16*)(ws + WOFFB);
  float* uout = (float*)(ws + UOUT_OFF);
  const int n_tok = in_sizes[0] / 20;

  prep_kernel<<<LUT_BLOCKS + REPACK_BLOCKS, 256, 0, stream>>>(
      E, W1, b1, W2, b2, W3, b3, HtW, HgW, PW, tab, wsb);
  ucompute_kernel<<<NKEYS / 16, 256, 0, stream>>>(
      tab, wsb, Htb, Hgb, Pb, uout);
  keyscatter_kernel<<<(n_tok + 63) / 64, 256, 0, stream>>>(ids, uout, out, n_tok);
}

// Round 24
// 27.496 us; speedup vs baseline: 1.3677x; 1.0287x over previous
//
#include <hip/hip_runtime.h>

// CharacterCNN — DEDUPE-BY-12-BIT-KEY, 3 dispatches.
// key = m3i:8 | st1:1 | st2:1 | st19:1 | st20:1. uout[4096][64] direct.
//  K0 prep: [bid 0..44]    parallel conv tables -> tab
//           [bid 45..492]  f16 frag-linear weight repack -> wsb
//           [bid 493..748] tokkey[t] for all tokens (independent work)
//  K1 ucompute (256 blocks, 16 keys): tab gather -> highway/proj MFMA from
//     frag-linear wsb -> uout.
//  K2 scatter (256 blocks, 256 tokens each): tokkey -> coalesced gather/store.

typedef _Float16 f16;
typedef __attribute__((ext_vector_type(8))) _Float16 f16x8;
typedef __attribute__((ext_vector_type(4))) float f32x4;

#define LC1   0
#define LRAW2 96
#define LT2   672
#define LRAW3 1696
#define LT3LO 5152
#define LT3HI 7200
// ws layout (bytes): tab f16[9248] @0; wsb @18944 (ends 276,992);
// tokkey u32[65536] @278528 (ends 540,672); uout f32[4096*64] @544768.
#define WOFFB    18944
#define PBASE    100352
#define NWTH     114688
#define TKEY_OFF 278528
#define UOUT_OFF 544768
#define NKEYS    4096
#define CROW     232
#define LUT_BLOCKS 45
#define REPACK_BLOCKS 448
#define KEY_BLOCKS 256

__device__ __forceinline__ f16x8 hmax8(f16x8 a, f16x8 b) {
  return __builtin_elementwise_max(a, b);
}

__device__ __forceinline__ f16x8 pin8(f16x8 v) {
  union { f16x8 v; unsigned w[4]; } x; x.v = v;
  asm volatile("" : "+v"(x.w[0]), "+v"(x.w[1]), "+v"(x.w[2]), "+v"(x.w[3]) :: "memory");
  return x.v;
}

__device__ __forceinline__ float xs(const float* __restrict__ E, int s, int i) {
  return (s == 0) ? 0.f : E[(s - 1) * 16 + i];
}

// ---------------- K0: tables + repack + keys ----------------
__global__ __launch_bounds__(256) void prep_kernel(
    const float* __restrict__ E,
    const float* __restrict__ W1, const float* __restrict__ b1,
    const float* __restrict__ W2, const float* __restrict__ b2,
    const float* __restrict__ W3, const float* __restrict__ b3,
    const float* __restrict__ HtW, const float* __restrict__ HgW,
    const float* __restrict__ PW, const int* __restrict__ ids,
    f16* __restrict__ tab, f16* __restrict__ wsb,
    unsigned* __restrict__ tokkey, int n_tok)
{
  const int tid = threadIdx.x;
  const int bid = blockIdx.x;

  if (bid >= LUT_BLOCKS + REPACK_BLOCKS) {   // ---- token keys ----
    int t = (bid - LUT_BLOCKS - REPACK_BLOCKS) * 256 + tid;
    if (t >= n_tok) return;
    const int4* idp4 = (const int4*)(ids + (size_t)t * 20);
    int st[21];
#pragma unroll
    for (int q = 0; q < 5; q++) {
      int4 v = idp4[q];
      st[q * 4 + 1] = v.x; st[q * 4 + 2] = v.y;   // raw 0/1
      st[q * 4 + 3] = v.z; st[q * 4 + 4] = v.w;
    }
    unsigned m3i = 0;
#pragma unroll
    for (int l = 1; l <= 18; l++)
      m3i |= 1u << ((st[l] << 2) | (st[l + 1] << 1) | st[l + 2]);
    tokkey[t] = m3i | ((unsigned)st[1] << 8) | ((unsigned)st[2] << 9)
              | ((unsigned)st[19] << 10) | ((unsigned)st[20] << 11);
    return;
  }

  if (bid >= LUT_BLOCKS) {              // ---- weight repack ----
    int idx = (bid - LUT_BLOCKS) * 256 + tid;
    if (idx < NWTH) {
      int e, isG = 0, isP = 0;
      if (idx < 50176)        { e = idx; }
      else if (idx < 100352)  { e = idx - 50176; isG = 1; }
      else                    { e = idx - 100352; isP = 1; }
      int col = e / 224, k = e - col * 224;
      int nf = col >> 4, kf = k >> 5, kr = k & 31;
      int lane = (col & 15) + ((kr >> 3) << 4), j = kr & 7;
      if (!isP) {
        int off = nf * 7168 + (isG * 7 + kf) * 512 + lane * 8 + j;
        wsb[off] = (f16)(isG ? HgW[e] : HtW[e]);
      } else {
        float w = PW[e];
        f16 hi = (f16)w;
        int off = PBASE + nf * 7168 + kf * 512 + lane * 8 + j;
        wsb[off] = hi;
        wsb[off + 3584] = (f16)(w - (float)hi);
      }
    }
    return;
  }

  // ---- table part: block-per-row, thread-per-channel ----
  if (bid < 27) {                       // LRAW3
    if (tid >= 128) return;
    const int c = tid, p = bid;
    const int sa = p / 9, sb = (p / 3) % 3, sc = p % 3;
    const float* w = W3 + c * 48;
    float acc = b3[c];
#pragma unroll
    for (int i = 0; i < 16; i++)
      acc += w[i * 3 + 0] * xs(E, sa, i) + w[i * 3 + 1] * xs(E, sb, i)
           + w[i * 3 + 2] * xs(E, sc, i);
    tab[LRAW3 + p * 128 + c] = (f16)acc;
    return;
  }
  if (bid < 43) {                       // LT3LO / LT3HI
    if (tid >= 128) return;
    const int c = tid, s = bid - 27;
    const float* w = W3 + c * 48;
    float lo = -65504.f, hi = -65504.f;
#pragma unroll
    for (int b = 0; b < 4; b++) {
      if (!((s >> b) & 1)) continue;
      int pl = 13 + 3 * (b >> 1) + (b & 1);
      int ph = 22 + 3 * (b >> 1) + (b & 1);
      int sal = pl / 9, sbl = (pl / 3) % 3, scl = pl % 3;
      int sah = ph / 9, sbh = (ph / 3) % 3, sch = ph % 3;
      float al = b3[c], ah = b3[c];
#pragma unroll
      for (int i = 0; i < 16; i++) {
        al += w[i * 3 + 0] * xs(E, sal, i) + w[i * 3 + 1] * xs(E, sbl, i)
            + w[i * 3 + 2] * xs(E, scl, i);
        ah += w[i * 3 + 0] * xs(E, sah, i) + w[i * 3 + 1] * xs(E, sbh, i)
            + w[i * 3 + 2] * xs(E, sch, i);
      }
      lo = fmaxf(lo, al);
      hi = fmaxf(hi, ah);
    }
    tab[LT3LO + s * 128 + c] = (f16)lo;
    tab[LT3HI + s * 128 + c] = (f16)hi;
    return;
  }
  if (bid == 43) {                      // LRAW2 + LT2
    const int c = tid & 63, part = tid >> 6;
    const float* w = W2 + c * 32;
    if (part < 2) {
      int p0 = part * 5;
      int pend = part ? 9 : 5;
      for (int p = p0; p < pend; p++) {
        int sa = p / 3, sb = p % 3;
        float acc = b2[c];
#pragma unroll
        for (int i = 0; i < 16; i++)
          acc += w[i * 2 + 0] * xs(E, sa, i) + w[i * 2 + 1] * xs(E, sb, i);
        tab[LRAW2 + p * 64 + c] = (f16)acc;
      }
    } else {
      float u[4];
#pragma unroll
      for (int b = 0; b < 4; b++) {
        int p = 4 + 3 * (b >> 1) + (b & 1);
        int sa = p / 3, sb = p % 3;
        float acc = b2[c];
#pragma unroll
        for (int i = 0; i < 16; i++)
          acc += w[i * 2 + 0] * xs(E, sa, i) + w[i * 2 + 1] * xs(E, sb, i);
        u[b] = acc;
      }
      int s0 = (part - 2) * 8;
#pragma unroll
      for (int j = 0; j < 8; j++) {
        int s = s0 + j;
        float m = -65504.f;
#pragma unroll
        for (int b = 0; b < 4; b++)
          if ((s >> b) & 1) m = fmaxf(m, u[b]);
        tab[LT2 + s * 64 + c] = (f16)m;
      }
    }
    return;
  }
  {                                     // LC1
    if (tid >= 32) return;
    const int c = tid;
    const float* w = W1 + c * 16;
    float u1 = b1[c], u2 = b1[c];
#pragma unroll
    for (int i = 0; i < 16; i++) {
      u1 += w[i] * E[i];
      u2 += w[i] * E[16 + i];
    }
    tab[LC1 + 0 * 32 + c] = (f16)fmaxf(u1, u2);
    tab[LC1 + 1 * 32 + c] = (f16)u1;
    tab[LC1 + 2 * 32 + c] = (f16)u2;
  }
}

// ---------------- K1: ucompute (R23 verbatim) ----------------
__global__ __launch_bounds__(256) void ucompute_kernel(
    const f16* __restrict__ tab, const f16* __restrict__ wsb,
    const float* __restrict__ Htb, const float* __restrict__ Hgb,
    const float* __restrict__ Pb, float* __restrict__ uout)
{
  __shared__ __attribute__((aligned(16))) f16 cnn[16 * CROW];

  const int tid = threadIdx.x;
  const int wave = tid >> 6, lane = tid & 63;
  const int kbase = blockIdx.x * 16;
  const int lrow = lane & 15;
  const int kg8 = (lane >> 4) * 8;
  const int rr0 = (lane >> 4) * 4;

  const int p1row = tid >> 4;
  const int p1g = tid & 15;
  unsigned mw, mb;
  {
    unsigned key = (unsigned)(kbase + p1row);
    unsigned m3i = key & 255u;
    int st1 = 1 + (int)((key >> 8) & 1),  st2 = 1 + (int)((key >> 9) & 1);
    int st19 = 1 + (int)((key >> 10) & 1), st20 = 1 + (int)((key >> 11) & 1);
    unsigned m2i = 0, mchar = 0;
#pragma unroll
    for (int p = 0; p < 8; p++)
      if ((m3i >> p) & 1) {
        m2i |= (1u << (p >> 1)) | (1u << (p & 3));
        mchar |= (1u << ((p >> 2) & 1)) | (1u << ((p >> 1) & 1)) | (1u << (p & 1));
      }
    unsigned sel = (mchar == 3u) ? 0u : ((mchar & 1u) ? 1u : 2u);
    mw = m3i | (m2i << 8) | (sel << 12);
    mb = (unsigned)st1 | ((unsigned)(st20 * 3) << 4)
       | ((unsigned)(st1 * 3 + st2) << 8) | ((unsigned)(st19 * 9 + st20 * 3) << 16);
  }

  const f16x8 KZ = {0, 0, 0, 0, 0, 0, 0, 0};
  {
    const int m3 = mw & 255;
    f16x8 v = hmax8(*(const f16x8*)(tab + LT3LO + (m3 & 15) * 128 + p1g * 8),
                    *(const f16x8*)(tab + LT3HI + ((m3 >> 4) & 15) * 128 + p1g * 8));
    v = hmax8(v, *(const f16x8*)(tab + LRAW3 + ((mb >> 8) & 15) * 128 + p1g * 8));
    v = hmax8(v, *(const f16x8*)(tab + LRAW3 + ((mb >> 16) & 31) * 128 + p1g * 8));
    *(f16x8*)&cnn[p1row * CROW + 96 + p1g * 8] = hmax8(v, KZ);
    if (p1g < 8) {
      f16x8 u = *(const f16x8*)(tab + LT2 + ((mw >> 8) & 15) * 64 + p1g * 8);
      u = hmax8(u, *(const f16x8*)(tab + LRAW2 + (mb & 15) * 64 + p1g * 8));
      u = hmax8(u, *(const f16x8*)(tab + LRAW2 + ((mb >> 4) & 15) * 64 + p1g * 8));
      *(f16x8*)&cnn[p1row * CROW + 32 + p1g * 8] = hmax8(u, KZ);
    }
    if (p1g < 4) {
      int sel = (mw >> 12) & 3;
      f16x8 w = *(const f16x8*)(tab + LC1 + sel * 32 + p1g * 8);
      *(f16x8*)&cnn[p1row * CROW + p1g * 8] = hmax8(w, KZ);
    }
  }
  __syncthreads();

  f16x8 af[7];
#pragma unroll
  for (int kf = 0; kf < 7; kf++)
    af[kf] = *(const f16x8*)&cnn[lrow * CROW + kf * 32 + kg8];
#pragma unroll
  for (int kf = 0; kf < 7; kf++) af[kf] = pin8(af[kf]);
  __syncthreads();   // all waves captured af before in-place hw writes

  const f16* wbase = wsb + lane * 8;
  const int nf_cnt = (wave < 2) ? 4 : 3;
  for (int i = 0; i < nf_cnt; i++) {
    const int nf = wave + i * 4;
    const int col = nf * 16 + lrow;
    const f16* p_ = wbase + nf * 7168;
    const float bt = Htb[col], bg = Hgb[col];
    f32x4 aT = {bt, bt, bt, bt};
    f32x4 aG = {bg, bg, bg, bg};
#pragma unroll
    for (int kf = 0; kf < 7; kf++) {
      f16x8 wTv = *(const f16x8*)(p_ + kf * 512);
      f16x8 wGv = *(const f16x8*)(p_ + 3584 + kf * 512);
      aT = __builtin_amdgcn_mfma_f32_16x16x32_f16(af[kf], wTv, aT, 0, 0, 0);
      aG = __builtin_amdgcn_mfma_f32_16x16x32_f16(af[kf], wGv, aG, 0, 0, 0);
    }
#pragma unroll
    for (int r = 0; r < 4; r++) {
      int row = rr0 + r;
      float t  = fmaxf(aT[r], 0.f);
      float gg = __builtin_amdgcn_rcpf(1.f + __expf(-aG[r]));
      float cv = (float)cnn[row * CROW + col];
      cnn[row * CROW + col] = (f16)(cv + gg * (t - cv));
    }
  }
  __syncthreads();

  f16x8 ah[7];
#pragma unroll
  for (int kf = 0; kf < 7; kf++)
    ah[kf] = *(const f16x8*)&cnn[lrow * CROW + kf * 32 + kg8];
  {
    const int col = wave * 16 + lrow;
    const float bp = Pb[col];
    f32x4 ac = {bp, bp, bp, bp};
    const f16* ph = wbase + PBASE + wave * 7168;
#pragma unroll
    for (int kf = 0; kf < 7; kf++) {
      f16x8 wh = *(const f16x8*)(ph + kf * 512);
      f16x8 wl = *(const f16x8*)(ph + 3584 + kf * 512);
      ac = __builtin_amdgcn_mfma_f32_16x16x32_f16(ah[kf], wh, ac, 0, 0, 0);
      ac = __builtin_amdgcn_mfma_f32_16x16x32_f16(ah[kf], wl, ac, 0, 0, 0);
    }
#pragma unroll
    for (int r = 0; r < 4; r++)
      uout[(size_t)(kbase + rr0 + r) * 64 + col] = ac[r];
  }
}

// ---------------- K2: scatter, 256 tokens/block ----------------
__global__ __launch_bounds__(256) void scatter_kernel(
    const unsigned* __restrict__ tokkey, const float* __restrict__ uout,
    float* __restrict__ out, int n_tok)
{
  __shared__ unsigned keys[256];
  const int tid = threadIdx.x;
  const int tok0 = blockIdx.x * 256;

  {
    int t = tok0 + tid;
    keys[tid] = (t < n_tok) ? tokkey[t] : 0u;
  }
  __syncthreads();

  const int tl = tid >> 2, q = tid & 3;
#pragma unroll
  for (int seg = 0; seg < 4; seg++) {
    const int t = tok0 + seg * 64 + tl;
    if (t >= n_tok) break;
    const f32x4* src =
        (const f32x4*)(uout + (size_t)keys[seg * 64 + tl] * 64 + q * 16);
    f32x4 v0 = src[0], v1 = src[1], v2 = src[2], v3 = src[3];
    f32x4* dst = (f32x4*)(out + (size_t)t * 64 + q * 16);
    dst[0] = v0; dst[1] = v1; dst[2] = v2; dst[3] = v3;
  }
}

extern "C" void kernel_launch(void* const* d_in, const int* in_sizes, int n_in,
                              void* d_out, int out_size, void* d_ws, size_t ws_size,
                              hipStream_t stream) {
  const int*   ids = (const int*)d_in[0];
  const float* E   = (const float*)d_in[1];
  const float* W1  = (const float*)d_in[2];
  const float* b1  = (const float*)d_in[3];
  const float* W2  = (const float*)d_in[4];
  const float* b2  = (const float*)d_in[5];
  const float* W3  = (const float*)d_in[6];
  const float* b3  = (const float*)d_in[7];
  const float* HtW = (const float*)d_in[8];
  const float* Htb = (const float*)d_in[9];
  const float* HgW = (const float*)d_in[10];
  const float* Hgb = (const float*)d_in[11];
  const float* PW  = (const float*)d_in[12];
  const float* Pb  = (const float*)d_in[13];
  float* out = (float*)d_out;
  char* ws = (char*)d_ws;
  f16* tab = (f16*)ws;
  f16* wsb = (f16*)(ws + WOFFB);
  unsigned* tokkey = (unsigned*)(ws + TKEY_OFF);
  float* uout = (float*)(ws + UOUT_OFF);
  const int n_tok = in_sizes[0] / 20;

  const int key_blocks = (n_tok + 255) / 256;
  prep_kernel<<<LUT_BLOCKS + REPACK_BLOCKS + key_blocks, 256, 0, stream>>>(
      E, W1, b1, W2, b2, W3, b3, HtW, HgW, PW, ids, tab, wsb, tokkey, n_tok);
  ucompute_kernel<<<NKEYS / 16, 256, 0, stream>>>(
      tab, wsb, Htb, Hgb, Pb, uout);
  scatter_kernel<<<(n_tok + 255) / 256, 256, 0, stream>>>(
      tokkey, uout, out, n_tok);
}